// Round 11
// baseline (108.894 us; speedup 1.0000x reference)
//
#include <hip/hip_runtime.h>

#define MT_EPS     1e-8f
#define GRID_N     8
#define NCELLS     64          // GRID_N^2
#define DOM        3.2f
#define INV_CELL   1.25f       // GRID_N / (2*DOM)
#define PAD        1e-3f       // conservative AABB pad >> fp slack of u/v tests
#define PT_BATCH   2048        // points per work item (8/thread * 256)
#define TRI_CHUNK  64          // tris per work item (staged to LDS, 3 KB)
#define K_ROWS     32          // max chunks/cell = ceil(F/TRI_CHUNK)
#define ITEM_CAP   8192

__device__ __forceinline__ int cell_clamp(float x) {
    int c = (int)floorf((x + DOM) * INV_CELL);
    return c < 0 ? 0 : (c > GRID_N - 1 ? GRID_N - 1 : c);
}

// ---- K1: 256-thread blocks, 1 tri/pt per thread (R10: 18 fat blocks = 7% of
//      CUs made bin/scatter latency-bound). Histograms stored TRANSPOSED
//      [cell][block] so build's scans read contiguous rows.
__global__ __launch_bounds__(256) void mt_bin(
    const float* __restrict__ v1, const float* __restrict__ v2,
    const float* __restrict__ v3, const float* __restrict__ pts,
    float4* __restrict__ coef, int* __restrict__ rangePk,
    int* __restrict__ pcell, int* __restrict__ triBH, int* __restrict__ ptBH,
    int F, int npts, int nTriB, int nPtB)
{
    __shared__ int h[NCELLS];
    if (threadIdx.x < NCELLS) h[threadIdx.x] = 0;
    __syncthreads();
    if ((int)blockIdx.x < nTriB) {
        int f = blockIdx.x * 256 + threadIdx.x;
        if (f < F) {
            float v1x=v1[3*f], v1y=v1[3*f+1], v1z=v1[3*f+2];
            float v2x=v2[3*f], v2y=v2[3*f+1], v2z=v2[3*f+2];
            float v3x=v3[3*f], v3y=v3[3*f+1], v3z=v3[3*f+2];
            float e1x=v2x-v1x, e1y=v2y-v1y, e1z=v2z-v1z;
            float e2x=v3x-v1x, e2y=v3y-v1y, e2z=v3z-v1z;
            float hx=-e2y, hy=e2x;                          // cross((0,0,1), e2)
            float a = e1x*hx + e1y*hy;                      // determinant
            float fi = (fabsf(a) > MT_EPS) ? (1.0f/a) : 0.0f; // invalid -> zero coefs -> miss
            float cux=fi*hx, cuy=fi*hy;
            float cu0 = -(v1x*cux + v1y*cuy);
            float cvx=fi*e1y, cvy=-fi*e1x;
            float cv0 = -(v1x*cvx + v1y*cvy);
            float nx=e1y*e2z-e1z*e2y, ny=e1z*e2x-e1x*e2z, nz=e1x*e2y-e1y*e2x;
            float ctx=fi*nx, cty=fi*ny, ctz=fi*nz;
            float ct0 = -(v1x*ctx + v1y*cty + v1z*ctz) - MT_EPS;
            coef[3*f+0] = make_float4(cux, cuy, cu0, cvx);
            coef[3*f+1] = make_float4(cvy, cv0, ctx, cty);
            coef[3*f+2] = make_float4(ctz, ct0, 0.0f, 0.0f);
            float xmn = fminf(v1x, fminf(v2x, v3x)) - PAD;
            float xmx = fmaxf(v1x, fmaxf(v2x, v3x)) + PAD;
            float ymn = fminf(v1y, fminf(v2y, v3y)) - PAD;
            float ymx = fmaxf(v1y, fmaxf(v2y, v3y)) + PAD;
            int cx0 = cell_clamp(xmn), cx1 = cell_clamp(xmx);
            int cy0 = cell_clamp(ymn), cy1 = cell_clamp(ymx);
            rangePk[f] = cx0 | (cx1 << 8) | (cy0 << 16) | (cy1 << 24);
            for (int cy = cy0; cy <= cy1; ++cy)
                for (int cx = cx0; cx <= cx1; ++cx)
                    atomicAdd(&h[cy * GRID_N + cx], 1);     // LDS atomic
        }
        __syncthreads();
        if (threadIdx.x < NCELLS)
            triBH[threadIdx.x * nTriB + blockIdx.x] = h[threadIdx.x];
    } else {
        int b = (int)blockIdx.x - nTriB;
        int p = b * 256 + threadIdx.x;
        if (p < npts) {
            int c = cell_clamp(pts[3*p+1]) * GRID_N + cell_clamp(pts[3*p]);
            pcell[p] = c;
            atomicAdd(&h[c], 1);                            // LDS atomic
        }
        __syncthreads();
        if (threadIdx.x < NCELLS)
            ptBH[threadIdx.x * nPtB + b] = h[threadIdx.x];
    }
}

// ---- K2: ONE block. Per-cell scans over transposed rows write per-(cell,
//      block) bases in place; cell-level offsets folded in a parallel pass.
//      cellMeta: [0..63] ptStart, [64] total, [65..128] nchunk.
//      Item: x=spOff y=ptCnt z=triOff w=triCnt|(chunkIdx<<16)
__global__ __launch_bounds__(256) void mt_build(
    const int* __restrict__ triBH, const int* __restrict__ ptBH,
    int* __restrict__ triBase, int* __restrict__ ptBase,
    int* __restrict__ cellMeta, int* __restrict__ origIdx,
    int4* __restrict__ items, int* __restrict__ nItemsOut,
    int nTriB, int nPtB)
{
    __shared__ int entC[NCELLS], ptC[NCELLS];
    __shared__ int entOff[NCELLS], ptOff[NCELLS], itOff[NCELLS];
    int tid = threadIdx.x;
    if (tid < NCELLS) {                         // per-cell scans (contiguous rows)
        int run = 0;
        for (int b = 0; b < nTriB; ++b) {
            int v = triBH[tid * nTriB + b]; triBase[tid * nTriB + b] = run; run += v;
        }
        entC[tid] = run;
        int rp = 0;
        for (int b = 0; b < nPtB; ++b) {
            int v = ptBH[tid * nPtB + b]; ptBase[tid * nPtB + b] = rp; rp += v;
        }
        ptC[tid] = rp;
    }
    __syncthreads();
    if (tid == 0) {                             // cell-level exclusive scans
        int to = 0, po = 0, io = 0;
        for (int c = 0; c < NCELLS; ++c) {
            entOff[c] = to; to += entC[c];
            ptOff[c]  = po; po += (ptC[c] + 7) & ~7;        // 8-aligned segments
            int ni = ((ptC[c] + PT_BATCH - 1) / PT_BATCH)
                   * ((entC[c] + TRI_CHUNK - 1) / TRI_CHUNK);
            itOff[c] = io; io += ni;
        }
        nItemsOut[0] = io < ITEM_CAP ? io : ITEM_CAP;
        cellMeta[NCELLS] = po;                              // total sorted slots
    }
    __syncthreads();
    for (int i = tid; i < NCELLS * nTriB; i += 256)         // fold cell offsets
        triBase[i] += entOff[i / nTriB];
    for (int i = tid; i < NCELLS * nPtB;  i += 256)
        ptBase[i]  += ptOff[i / nPtB];
    if (tid < NCELLS) {
        int c = tid;
        int nk = (entC[c] + TRI_CHUNK - 1) / TRI_CHUNK;
        cellMeta[c] = ptOff[c];
        cellMeta[NCELLS + 1 + c] = nk;
        int e = ptOff[c] + ptC[c], ae = ptOff[c] + ((ptC[c] + 7) & ~7);
        for (int q = e; q < ae; ++q) origIdx[q] = -1;       // pad slots skipped in mt_out
        int idx = itOff[c], pc = ptC[c], tc = entC[c];
        for (int i = 0; i < pc; i += PT_BATCH)
            for (int k = 0; k < nk; ++k) {
                if (idx < ITEM_CAP) {
                    int j = k * TRI_CHUNK;
                    int tcnt = tc - j; if (tcnt > TRI_CHUNK) tcnt = TRI_CHUNK;
                    int pcnt = pc - i; if (pcnt > PT_BATCH)  pcnt = PT_BATCH;
                    items[idx] = make_int4(ptOff[c] + i, pcnt, entOff[c] + j,
                                           tcnt | (k << 16));
                }
                ++idx;
            }
    }
}

// ---- K3: scatter, 256-thread blocks matching mt_bin's partitioning exactly.
//      Block-local LDS ranks + transposed per-(cell,block) bases; plain
//      stores only (no global atomics anywhere in this kernel).
__global__ __launch_bounds__(256) void mt_scatter(
    const float* __restrict__ pts, const int* __restrict__ rangePk,
    const int* __restrict__ pcell, const int* __restrict__ triBase,
    const int* __restrict__ ptBase, int* __restrict__ cellTriIdx,
    float* __restrict__ sortedPts, int* __restrict__ origIdx,
    int F, int npts, int nTriB, int nPtB)
{
    __shared__ int h[NCELLS];
    if (threadIdx.x < NCELLS) h[threadIdx.x] = 0;
    __syncthreads();
    if ((int)blockIdx.x < nTriB) {
        int f = blockIdx.x * 256 + threadIdx.x;
        if (f < F) {
            int r = rangePk[f];
            int cx0 = r & 255, cx1 = (r >> 8) & 255;
            int cy0 = (r >> 16) & 255, cy1 = (r >> 24) & 255;
            for (int cy = cy0; cy <= cy1; ++cy)
                for (int cx = cx0; cx <= cx1; ++cx) {
                    int c = cy * GRID_N + cx;
                    int rank = atomicAdd(&h[c], 1);         // LDS atomic
                    cellTriIdx[triBase[c * nTriB + blockIdx.x] + rank] = f;
                }
        }
    } else {
        int b = (int)blockIdx.x - nTriB;
        int p = b * 256 + threadIdx.x;
        if (p < npts) {
            float X = pts[3*p], Y = pts[3*p+1], Z = pts[3*p+2];
            int c = pcell[p];
            int rank = atomicAdd(&h[c], 1);                 // LDS atomic
            int pos = ptBase[c * nPtB + b] + rank;
            sortedPts[3*pos+0] = X;
            sortedPts[3*pos+1] = Y;
            sortedPts[3*pos+2] = Z;
            origIdx[pos] = p;
        }
    }
}

// ---- K4: main. Per item: stage <=64 tri coefs to LDS; ACTIVE threads
//      (tid*8 < ptCnt) load 8 sorted points coalesced, 13-VALU/test loop,
//      store 8 ushort counts as one uint4. No atomics.
__global__ __launch_bounds__(256) void mt_main(
    const int4* __restrict__ items, const int* __restrict__ nItemsPtr,
    const float* __restrict__ sortedPts, const float4* __restrict__ coef,
    const int* __restrict__ cellTriIdx, unsigned short* __restrict__ partial,
    int nppad)
{
    __shared__ float4 sc[TRI_CHUNK * 3];       // 3 KB
    int nIt = *nItemsPtr;
    for (int b = blockIdx.x; b < nIt; b += gridDim.x) {
        int4 it = items[b];                    // x=spOff y=ptCnt z=triOff w=tcnt|(chunk<<16)
        int tcnt = it.w & 0xffff;
        int krow = it.w >> 16;
        int n3 = tcnt * 3;
        for (int i = threadIdx.x; i < n3; i += 256) {
            int tri = cellTriIdx[it.z + i / 3];
            sc[i] = coef[tri * 3 + i % 3];
        }
        __syncthreads();

        if ((int)threadIdx.x * 8 < it.y) {     // active threads tile the padded segment
            int sp0 = it.x + threadIdx.x * 8;  // it.x 8-aligned -> 16B-aligned loads
            const float4* pv = (const float4*)(sortedPts + (size_t)sp0 * 3);
            float4 A = pv[0], B = pv[1], C = pv[2], D = pv[3], E = pv[4], G = pv[5];
            float px[8] = {A.x, A.w, B.z, C.y, D.x, D.w, E.z, G.y};
            float py[8] = {A.y, B.x, B.w, C.z, D.y, E.x, E.w, G.z};
            float pz[8] = {A.z, B.y, C.x, C.w, D.z, E.y, G.x, G.w};
            int cnt[8];
            #pragma unroll
            for (int k = 0; k < 8; ++k) cnt[k] = 0;

            #pragma unroll 2
            for (int j = 0; j < tcnt; ++j) {
                float4 c0 = sc[3*j+0];                       // uniform ds_read_b128
                float4 c1 = sc[3*j+1];
                float2 c2 = *(const float2*)&sc[3*j+2];      // uniform ds_read_b64
                #pragma unroll
                for (int k = 0; k < 8; ++k) {
                    float u = fmaf(c0.x, px[k], fmaf(c0.y, py[k], c0.z));
                    float v = fmaf(c0.w, px[k], fmaf(c1.x, py[k], c1.y));
                    float t = fmaf(c1.z, px[k], fmaf(c1.w, py[k], fmaf(c2.x, pz[k], c2.y)));
                    float w = 1.0f - (u + v);
                    float m = fminf(fminf(fminf(u, v), t), w);   // v_min3 + v_min
                    cnt[k] += __float_as_int(m) >> 31;           // -1 per miss
                }
            }
            uint4 o;   // hits = tcnt + cnt[k]; pad slots garbage but origIdx=-1
            o.x = (unsigned)(unsigned short)(tcnt + cnt[0]) | ((unsigned)(unsigned short)(tcnt + cnt[1]) << 16);
            o.y = (unsigned)(unsigned short)(tcnt + cnt[2]) | ((unsigned)(unsigned short)(tcnt + cnt[3]) << 16);
            o.z = (unsigned)(unsigned short)(tcnt + cnt[4]) | ((unsigned)(unsigned short)(tcnt + cnt[5]) << 16);
            o.w = (unsigned)(unsigned short)(tcnt + cnt[6]) | ((unsigned)(unsigned short)(tcnt + cnt[7]) << 16);
            *(uint4*)(partial + (size_t)krow * nppad + sp0) = o;
        }
        __syncthreads();                        // before restage
    }
}

// ---- K5: out[origIdx[sp]] = sum over k < nchunk(cell(sp)) of partial[k][sp].
__global__ __launch_bounds__(256) void mt_out(
    const unsigned short* __restrict__ partial, const int* __restrict__ cellMeta,
    const int* __restrict__ origIdx, float* __restrict__ out, int nppad)
{
    __shared__ int start[NCELLS + 1], nchk[NCELLS];
    int tid = threadIdx.x;
    if (tid < NCELLS + 1) start[tid] = cellMeta[tid];
    if (tid < NCELLS)     nchk[tid]  = cellMeta[NCELLS + 1 + tid];
    __syncthreads();
    int sp0 = (blockIdx.x * 256 + tid) * 4;
    if (sp0 >= start[NCELLS]) return;
    int lo = 0, hi = NCELLS - 1;
    while (lo < hi) { int mid = (lo + hi) >> 1; if (start[mid+1] <= sp0) lo = mid + 1; else hi = mid; }
    int nk = nchk[lo];
    int s0 = 0, s1 = 0, s2 = 0, s3 = 0;
    for (int k = 0; k < nk; ++k) {
        uint2 v = *(const uint2*)(partial + (size_t)k * nppad + sp0);
        s0 += v.x & 0xffff; s1 += v.x >> 16;
        s2 += v.y & 0xffff; s3 += v.y >> 16;
    }
    int4 oi = *(const int4*)(origIdx + sp0);
    if (oi.x >= 0) out[oi.x] = (float)s0;
    if (oi.y >= 0) out[oi.y] = (float)s1;
    if (oi.z >= 0) out[oi.z] = (float)s2;
    if (oi.w >= 0) out[oi.w] = (float)s3;
}

extern "C" void kernel_launch(void* const* d_in, const int* in_sizes, int n_in,
                              void* d_out, int out_size, void* d_ws, size_t ws_size,
                              hipStream_t stream) {
    const float* pts = (const float*)d_in[0];   // [B,N,3]
    const float* v1  = (const float*)d_in[1];   // [F,3]
    const float* v2  = (const float*)d_in[2];
    const float* v3  = (const float*)d_in[3];
    float* out = (float*)d_out;                  // [B*N] counts
    int npts = in_sizes[0] / 3;                  // 65536
    int F    = in_sizes[1] / 3;                  // 2048

    int nTriB = (F + 255) / 256;                 // 8
    int nPtB  = (npts + 255) / 256;              // 256
    int nppad = (npts + 8 * NCELLS + 7) & ~7;    // sorted-slot capacity

    // ---- workspace layout (16B-aligned chunks), total ~6.6 MB (ws >= 8.5 MB) ----
    char* w = (char*)d_ws;
    size_t off = 0;
    auto take = [&](size_t bytes) { void* p = w + off; off = (off + bytes + 15) & ~(size_t)15; return p; };
    float4* coef       = (float4*)take((size_t)F * 3 * sizeof(float4));
    int*    rangePk    = (int*)   take((size_t)F * sizeof(int));
    int*    pcell      = (int*)   take((size_t)npts * sizeof(int));
    int*    triBH      = (int*)   take((size_t)nTriB * NCELLS * sizeof(int));
    int*    ptBH       = (int*)   take((size_t)nPtB * NCELLS * sizeof(int));
    int*    triBase    = (int*)   take((size_t)nTriB * NCELLS * sizeof(int));
    int*    ptBase     = (int*)   take((size_t)nPtB * NCELLS * sizeof(int));
    int*    cellMeta   = (int*)   take((2 * NCELLS + 1) * sizeof(int));
    int*    nItems     = (int*)   take(sizeof(int));
    int4*   itemsBuf   = (int4*)  take((size_t)ITEM_CAP * sizeof(int4));
    int*    origIdx    = (int*)   take((size_t)nppad * sizeof(int));
    float*  sortedPts  = (float*) take((size_t)nppad * 3 * sizeof(float));
    int*    cellTriIdx = (int*)   take((size_t)F * NCELLS * sizeof(int));
    unsigned short* partial = (unsigned short*)take((size_t)K_ROWS * nppad * sizeof(unsigned short));
    (void)ws_size;

    mt_bin    <<<dim3(nTriB + nPtB), dim3(256), 0, stream>>>(
                 v1, v2, v3, pts, coef, rangePk, pcell, triBH, ptBH,
                 F, npts, nTriB, nPtB);
    mt_build  <<<dim3(1), dim3(256), 0, stream>>>(
                 triBH, ptBH, triBase, ptBase, cellMeta, origIdx, itemsBuf,
                 nItems, nTriB, nPtB);
    mt_scatter<<<dim3(nTriB + nPtB), dim3(256), 0, stream>>>(
                 pts, rangePk, pcell, triBase, ptBase, cellTriIdx,
                 sortedPts, origIdx, F, npts, nTriB, nPtB);
    mt_main   <<<dim3(1024), dim3(256), 0, stream>>>(
                 itemsBuf, nItems, sortedPts, coef, cellTriIdx, partial, nppad);
    int nq = (nppad + 3) / 4;
    mt_out    <<<dim3((nq + 255) / 256), dim3(256), 0, stream>>>(
                 partial, cellMeta, origIdx, out, nppad);
}

// Round 12
// 78.938 us; speedup vs baseline: 1.3795x; 1.3795x over previous
//
#include <hip/hip_runtime.h>

#define MT_EPS     1e-8f
#define GRID_N     8
#define NCELLS     64          // GRID_N^2
#define DOM        3.2f
#define INV_CELL   1.25f       // GRID_N / (2*DOM)
#define PAD        1e-3f       // conservative AABB pad >> fp slack of u/v tests
#define PT_BATCH   2048        // points per work item (8/thread * 256)
#define TRI_CHUNK  64          // tris per work item (staged to LDS, 3 KB)
#define K_ROWS     32          // max chunks/cell = ceil(F/TRI_CHUNK)
#define ITEM_CAP   8192
#define MAX_PTB    256         // LDS sizing: nPtB <= 256 (npts <= 65536)
#define MAX_TRIB   8           // nTriB <= 8 (F <= 2048)

__device__ __forceinline__ int cell_clamp(float x) {
    int c = (int)floorf((x + DOM) * INV_CELL);
    return c < 0 ? 0 : (c > GRID_N - 1 ? GRID_N - 1 : c);
}

// ---- K1: 256-thread blocks, 1 tri/pt per thread. Histograms TRANSPOSED
//      [cell][block] as USHORT (counts <= 256/block) so build can stage all
//      of them in LDS (R11: un-staged global scans made build 55us).
__global__ __launch_bounds__(256) void mt_bin(
    const float* __restrict__ v1, const float* __restrict__ v2,
    const float* __restrict__ v3, const float* __restrict__ pts,
    float4* __restrict__ coef, int* __restrict__ rangePk,
    int* __restrict__ pcell, unsigned short* __restrict__ triBH,
    unsigned short* __restrict__ ptBH, int F, int npts, int nTriB, int nPtB)
{
    __shared__ int h[NCELLS];
    if (threadIdx.x < NCELLS) h[threadIdx.x] = 0;
    __syncthreads();
    if ((int)blockIdx.x < nTriB) {
        int f = blockIdx.x * 256 + threadIdx.x;
        if (f < F) {
            float v1x=v1[3*f], v1y=v1[3*f+1], v1z=v1[3*f+2];
            float v2x=v2[3*f], v2y=v2[3*f+1], v2z=v2[3*f+2];
            float v3x=v3[3*f], v3y=v3[3*f+1], v3z=v3[3*f+2];
            float e1x=v2x-v1x, e1y=v2y-v1y, e1z=v2z-v1z;
            float e2x=v3x-v1x, e2y=v3y-v1y, e2z=v3z-v1z;
            float hx=-e2y, hy=e2x;                          // cross((0,0,1), e2)
            float a = e1x*hx + e1y*hy;                      // determinant
            float fi = (fabsf(a) > MT_EPS) ? (1.0f/a) : 0.0f; // invalid -> zero coefs -> miss
            float cux=fi*hx, cuy=fi*hy;
            float cu0 = -(v1x*cux + v1y*cuy);
            float cvx=fi*e1y, cvy=-fi*e1x;
            float cv0 = -(v1x*cvx + v1y*cvy);
            float nx=e1y*e2z-e1z*e2y, ny=e1z*e2x-e1x*e2z, nz=e1x*e2y-e1y*e2x;
            float ctx=fi*nx, cty=fi*ny, ctz=fi*nz;
            float ct0 = -(v1x*ctx + v1y*cty + v1z*ctz) - MT_EPS;
            coef[3*f+0] = make_float4(cux, cuy, cu0, cvx);
            coef[3*f+1] = make_float4(cvy, cv0, ctx, cty);
            coef[3*f+2] = make_float4(ctz, ct0, 0.0f, 0.0f);
            float xmn = fminf(v1x, fminf(v2x, v3x)) - PAD;
            float xmx = fmaxf(v1x, fmaxf(v2x, v3x)) + PAD;
            float ymn = fminf(v1y, fminf(v2y, v3y)) - PAD;
            float ymx = fmaxf(v1y, fmaxf(v2y, v3y)) + PAD;
            int cx0 = cell_clamp(xmn), cx1 = cell_clamp(xmx);
            int cy0 = cell_clamp(ymn), cy1 = cell_clamp(ymx);
            rangePk[f] = cx0 | (cx1 << 8) | (cy0 << 16) | (cy1 << 24);
            for (int cy = cy0; cy <= cy1; ++cy)
                for (int cx = cx0; cx <= cx1; ++cx)
                    atomicAdd(&h[cy * GRID_N + cx], 1);     // LDS atomic
        }
        __syncthreads();
        if (threadIdx.x < NCELLS)
            triBH[threadIdx.x * nTriB + blockIdx.x] = (unsigned short)h[threadIdx.x];
    } else {
        int b = (int)blockIdx.x - nTriB;
        int p = b * 256 + threadIdx.x;
        if (p < npts) {
            int c = cell_clamp(pts[3*p+1]) * GRID_N + cell_clamp(pts[3*p]);
            pcell[p] = c;
            atomicAdd(&h[c], 1);                            // LDS atomic
        }
        __syncthreads();
        if (threadIdx.x < NCELLS)
            ptBH[threadIdx.x * nPtB + b] = (unsigned short)h[threadIdx.x];
    }
}

// ---- K2: ONE block. ALL histograms staged to LDS (33KB, coalesced uint4),
//      then: 4-thread/cell quarter scans -> per-cell quarter-base scan ->
//      thread-0 cell-offset scan (LDS only) -> parallel base write-back ->
//      item emission. cellMeta: [0..63] ptStart, [64] total, [65..128] nchunk.
//      Item: x=spOff y=ptCnt z=triOff w=triCnt|(chunkIdx<<16)
__global__ __launch_bounds__(256) void mt_build(
    const unsigned short* __restrict__ triBH, const unsigned short* __restrict__ ptBH,
    int* __restrict__ triBase, int* __restrict__ ptBase,
    int* __restrict__ cellMeta, int* __restrict__ origIdx,
    int4* __restrict__ items, int* __restrict__ nItemsOut,
    int nTriB, int nPtB)
{
    __shared__ unsigned short sPH[NCELLS * MAX_PTB];   // 32 KB
    __shared__ unsigned short sTH[NCELLS * MAX_TRIB];  // 1 KB
    __shared__ int qbase[NCELLS][4];                   // quarter exclusive bases
    __shared__ int entC[NCELLS], ptC[NCELLS];
    __shared__ int entOff[NCELLS], ptOff[NCELLS], itOff[NCELLS];
    int tid = threadIdx.x;

    // Stage histograms (coalesced; totals divisible by 8 for our sizes).
    int nPH = NCELLS * nPtB, nTH = NCELLS * nTriB;
    for (int i = tid; i < nPH / 8; i += 256) ((uint4*)sPH)[i] = ((const uint4*)ptBH)[i];
    for (int i = (nPH / 8) * 8 + tid; i < nPH; i += 256) sPH[i] = ptBH[i];
    for (int i = tid; i < nTH / 8; i += 256) ((uint4*)sTH)[i] = ((const uint4*)triBH)[i];
    for (int i = (nTH / 8) * 8 + tid; i < nTH; i += 256) sTH[i] = triBH[i];
    __syncthreads();

    // Quarter sums: 4 threads per cell.
    int qlen = (nPtB + 3) / 4;
    {
        int cell = tid >> 2, q = tid & 3;
        int b0 = q * qlen, b1 = min(b0 + qlen, nPtB);
        int s = 0;
        for (int b = b0; b < b1; ++b) s += sPH[cell * nPtB + b];
        qbase[cell][q] = s;
    }
    __syncthreads();
    if (tid < NCELLS) {                        // per-cell quarter scan + tri row sum
        int s0 = qbase[tid][0], s1 = qbase[tid][1], s2 = qbase[tid][2], s3 = qbase[tid][3];
        qbase[tid][0] = 0; qbase[tid][1] = s0; qbase[tid][2] = s0 + s1; qbase[tid][3] = s0 + s1 + s2;
        ptC[tid] = s0 + s1 + s2 + s3;
        int t = 0;
        for (int b = 0; b < nTriB; ++b) t += sTH[tid * nTriB + b];
        entC[tid] = t;
    }
    __syncthreads();
    if (tid == 0) {                            // cell-level exclusive scans (LDS only)
        int to = 0, po = 0, io = 0;
        for (int c = 0; c < NCELLS; ++c) {
            entOff[c] = to; to += entC[c];
            ptOff[c]  = po; po += (ptC[c] + 7) & ~7;        // 8-aligned segments
            int ni = ((ptC[c] + PT_BATCH - 1) / PT_BATCH)
                   * ((entC[c] + TRI_CHUNK - 1) / TRI_CHUNK);
            itOff[c] = io; io += ni;
        }
        nItemsOut[0] = io < ITEM_CAP ? io : ITEM_CAP;
        cellMeta[NCELLS] = po;                              // total sorted slots
    }
    __syncthreads();
    {   // ptBase write-back: 4 threads/cell, each re-scans its quarter from LDS
        int cell = tid >> 2, q = tid & 3;
        int b0 = q * qlen, b1 = min(b0 + qlen, nPtB);
        int run = ptOff[cell] + qbase[cell][q];
        for (int b = b0; b < b1; ++b) {
            ptBase[cell * nPtB + b] = run;
            run += sPH[cell * nPtB + b];
        }
    }
    if (tid < NCELLS) {                        // triBase write-back (8 values/cell)
        int run = entOff[tid];
        for (int b = 0; b < nTriB; ++b) {
            triBase[tid * nTriB + b] = run;
            run += sTH[tid * nTriB + b];
        }
    }
    if (tid < NCELLS) {
        int c = tid;
        int nk = (entC[c] + TRI_CHUNK - 1) / TRI_CHUNK;
        cellMeta[c] = ptOff[c];
        cellMeta[NCELLS + 1 + c] = nk;
        int e = ptOff[c] + ptC[c], ae = ptOff[c] + ((ptC[c] + 7) & ~7);
        for (int q = e; q < ae; ++q) origIdx[q] = -1;       // pad slots skipped in mt_out
        int idx = itOff[c], pc = ptC[c], tc = entC[c];
        for (int i = 0; i < pc; i += PT_BATCH)
            for (int k = 0; k < nk; ++k) {
                if (idx < ITEM_CAP) {
                    int j = k * TRI_CHUNK;
                    int tcnt = tc - j; if (tcnt > TRI_CHUNK) tcnt = TRI_CHUNK;
                    int pcnt = pc - i; if (pcnt > PT_BATCH)  pcnt = PT_BATCH;
                    items[idx] = make_int4(ptOff[c] + i, pcnt, entOff[c] + j,
                                           tcnt | (k << 16));
                }
                ++idx;
            }
    }
}

// ---- K3: scatter, 256-thread blocks matching mt_bin's partitioning.
//      Block-local LDS ranks + per-(cell,block) bases; plain stores only.
__global__ __launch_bounds__(256) void mt_scatter(
    const float* __restrict__ pts, const int* __restrict__ rangePk,
    const int* __restrict__ pcell, const int* __restrict__ triBase,
    const int* __restrict__ ptBase, int* __restrict__ cellTriIdx,
    float* __restrict__ sortedPts, int* __restrict__ origIdx,
    int F, int npts, int nTriB, int nPtB)
{
    __shared__ int h[NCELLS];
    if (threadIdx.x < NCELLS) h[threadIdx.x] = 0;
    __syncthreads();
    if ((int)blockIdx.x < nTriB) {
        int f = blockIdx.x * 256 + threadIdx.x;
        if (f < F) {
            int r = rangePk[f];
            int cx0 = r & 255, cx1 = (r >> 8) & 255;
            int cy0 = (r >> 16) & 255, cy1 = (r >> 24) & 255;
            for (int cy = cy0; cy <= cy1; ++cy)
                for (int cx = cx0; cx <= cx1; ++cx) {
                    int c = cy * GRID_N + cx;
                    int rank = atomicAdd(&h[c], 1);         // LDS atomic
                    cellTriIdx[triBase[c * nTriB + blockIdx.x] + rank] = f;
                }
        }
    } else {
        int b = (int)blockIdx.x - nTriB;
        int p = b * 256 + threadIdx.x;
        if (p < npts) {
            float X = pts[3*p], Y = pts[3*p+1], Z = pts[3*p+2];
            int c = pcell[p];
            int rank = atomicAdd(&h[c], 1);                 // LDS atomic
            int pos = ptBase[c * nPtB + b] + rank;
            sortedPts[3*pos+0] = X;
            sortedPts[3*pos+1] = Y;
            sortedPts[3*pos+2] = Z;
            origIdx[pos] = p;
        }
    }
}

// ---- K4: main. Per item: stage <=64 tri coefs to LDS; ACTIVE threads
//      (tid*8 < ptCnt) load 8 sorted points coalesced, 13-VALU/test loop,
//      store 8 ushort counts as one uint4. No atomics.
__global__ __launch_bounds__(256) void mt_main(
    const int4* __restrict__ items, const int* __restrict__ nItemsPtr,
    const float* __restrict__ sortedPts, const float4* __restrict__ coef,
    const int* __restrict__ cellTriIdx, unsigned short* __restrict__ partial,
    int nppad)
{
    __shared__ float4 sc[TRI_CHUNK * 3];       // 3 KB
    int nIt = *nItemsPtr;
    for (int b = blockIdx.x; b < nIt; b += gridDim.x) {
        int4 it = items[b];                    // x=spOff y=ptCnt z=triOff w=tcnt|(chunk<<16)
        int tcnt = it.w & 0xffff;
        int krow = it.w >> 16;
        int n3 = tcnt * 3;
        for (int i = threadIdx.x; i < n3; i += 256) {
            int tri = cellTriIdx[it.z + i / 3];
            sc[i] = coef[tri * 3 + i % 3];
        }
        __syncthreads();

        if ((int)threadIdx.x * 8 < it.y) {     // active threads tile the padded segment
            int sp0 = it.x + threadIdx.x * 8;  // it.x 8-aligned -> 16B-aligned loads
            const float4* pv = (const float4*)(sortedPts + (size_t)sp0 * 3);
            float4 A = pv[0], B = pv[1], C = pv[2], D = pv[3], E = pv[4], G = pv[5];
            float px[8] = {A.x, A.w, B.z, C.y, D.x, D.w, E.z, G.y};
            float py[8] = {A.y, B.x, B.w, C.z, D.y, E.x, E.w, G.z};
            float pz[8] = {A.z, B.y, C.x, C.w, D.z, E.y, G.x, G.w};
            int cnt[8];
            #pragma unroll
            for (int k = 0; k < 8; ++k) cnt[k] = 0;

            #pragma unroll 2
            for (int j = 0; j < tcnt; ++j) {
                float4 c0 = sc[3*j+0];                       // uniform ds_read_b128
                float4 c1 = sc[3*j+1];
                float2 c2 = *(const float2*)&sc[3*j+2];      // uniform ds_read_b64
                #pragma unroll
                for (int k = 0; k < 8; ++k) {
                    float u = fmaf(c0.x, px[k], fmaf(c0.y, py[k], c0.z));
                    float v = fmaf(c0.w, px[k], fmaf(c1.x, py[k], c1.y));
                    float t = fmaf(c1.z, px[k], fmaf(c1.w, py[k], fmaf(c2.x, pz[k], c2.y)));
                    float w = 1.0f - (u + v);
                    float m = fminf(fminf(fminf(u, v), t), w);   // v_min3 + v_min
                    cnt[k] += __float_as_int(m) >> 31;           // -1 per miss
                }
            }
            uint4 o;   // hits = tcnt + cnt[k]; pad slots garbage but origIdx=-1
            o.x = (unsigned)(unsigned short)(tcnt + cnt[0]) | ((unsigned)(unsigned short)(tcnt + cnt[1]) << 16);
            o.y = (unsigned)(unsigned short)(tcnt + cnt[2]) | ((unsigned)(unsigned short)(tcnt + cnt[3]) << 16);
            o.z = (unsigned)(unsigned short)(tcnt + cnt[4]) | ((unsigned)(unsigned short)(tcnt + cnt[5]) << 16);
            o.w = (unsigned)(unsigned short)(tcnt + cnt[6]) | ((unsigned)(unsigned short)(tcnt + cnt[7]) << 16);
            *(uint4*)(partial + (size_t)krow * nppad + sp0) = o;
        }
        __syncthreads();                        // before restage
    }
}

// ---- K5: 1 point/thread (258 blocks, coalesced ushort row reads):
//      out[origIdx[sp]] = sum over k < nchunk(cell(sp)) of partial[k][sp].
__global__ __launch_bounds__(256) void mt_out(
    const unsigned short* __restrict__ partial, const int* __restrict__ cellMeta,
    const int* __restrict__ origIdx, float* __restrict__ out, int nppad)
{
    __shared__ int start[NCELLS + 1], nchk[NCELLS];
    int tid = threadIdx.x;
    if (tid < NCELLS + 1) start[tid] = cellMeta[tid];
    if (tid < NCELLS)     nchk[tid]  = cellMeta[NCELLS + 1 + tid];
    __syncthreads();
    int sp = blockIdx.x * 256 + tid;
    if (sp >= start[NCELLS]) return;
    int oi = origIdx[sp];
    if (oi < 0) return;                         // pad slot
    int lo = 0, hi = NCELLS - 1;
    while (lo < hi) { int mid = (lo + hi) >> 1; if (start[mid+1] <= sp) lo = mid + 1; else hi = mid; }
    int nk = nchk[lo];
    int s = 0;
    for (int k = 0; k < nk; ++k)
        s += partial[(size_t)k * nppad + sp];   // consecutive threads: coalesced
    out[oi] = (float)s;
}

extern "C" void kernel_launch(void* const* d_in, const int* in_sizes, int n_in,
                              void* d_out, int out_size, void* d_ws, size_t ws_size,
                              hipStream_t stream) {
    const float* pts = (const float*)d_in[0];   // [B,N,3]
    const float* v1  = (const float*)d_in[1];   // [F,3]
    const float* v2  = (const float*)d_in[2];
    const float* v3  = (const float*)d_in[3];
    float* out = (float*)d_out;                  // [B*N] counts
    int npts = in_sizes[0] / 3;                  // 65536
    int F    = in_sizes[1] / 3;                  // 2048

    int nTriB = (F + 255) / 256;                 // 8
    int nPtB  = (npts + 255) / 256;              // 256
    int nppad = (npts + 8 * NCELLS + 7) & ~7;    // sorted-slot capacity

    // ---- workspace layout (16B-aligned chunks), total ~6.6 MB (ws >= 8.5 MB) ----
    char* w = (char*)d_ws;
    size_t off = 0;
    auto take = [&](size_t bytes) { void* p = w + off; off = (off + bytes + 15) & ~(size_t)15; return p; };
    float4* coef       = (float4*)take((size_t)F * 3 * sizeof(float4));
    int*    rangePk    = (int*)   take((size_t)F * sizeof(int));
    int*    pcell      = (int*)   take((size_t)npts * sizeof(int));
    unsigned short* triBH = (unsigned short*)take((size_t)nTriB * NCELLS * sizeof(unsigned short));
    unsigned short* ptBH  = (unsigned short*)take((size_t)nPtB * NCELLS * sizeof(unsigned short));
    int*    triBase    = (int*)   take((size_t)nTriB * NCELLS * sizeof(int));
    int*    ptBase     = (int*)   take((size_t)nPtB * NCELLS * sizeof(int));
    int*    cellMeta   = (int*)   take((2 * NCELLS + 1) * sizeof(int));
    int*    nItems     = (int*)   take(sizeof(int));
    int4*   itemsBuf   = (int4*)  take((size_t)ITEM_CAP * sizeof(int4));
    int*    origIdx    = (int*)   take((size_t)nppad * sizeof(int));
    float*  sortedPts  = (float*) take((size_t)nppad * 3 * sizeof(float));
    int*    cellTriIdx = (int*)   take((size_t)F * NCELLS * sizeof(int));
    unsigned short* partial = (unsigned short*)take((size_t)K_ROWS * nppad * sizeof(unsigned short));
    (void)ws_size;

    mt_bin    <<<dim3(nTriB + nPtB), dim3(256), 0, stream>>>(
                 v1, v2, v3, pts, coef, rangePk, pcell, triBH, ptBH,
                 F, npts, nTriB, nPtB);
    mt_build  <<<dim3(1), dim3(256), 0, stream>>>(
                 triBH, ptBH, triBase, ptBase, cellMeta, origIdx, itemsBuf,
                 nItems, nTriB, nPtB);
    mt_scatter<<<dim3(nTriB + nPtB), dim3(256), 0, stream>>>(
                 pts, rangePk, pcell, triBase, ptBase, cellTriIdx,
                 sortedPts, origIdx, F, npts, nTriB, nPtB);
    mt_main   <<<dim3(1024), dim3(256), 0, stream>>>(
                 itemsBuf, nItems, sortedPts, coef, cellTriIdx, partial, nppad);
    int nob = (nppad + 255) / 256;
    mt_out    <<<dim3(nob), dim3(256), 0, stream>>>(
                 partial, cellMeta, origIdx, out, nppad);
}